// Round 4
// baseline (16398.566 us; speedup 1.0000x reference)
//
#include <hip/hip_runtime.h>
#include <math.h>

#define HID 1024
#define SEQ 4096
#define NWG 64        // 64 WGs x 256 thr = 256 waves; co-resident on 256 CUs
#define BT  8         // t-tile for the U GEMM

typedef float v4f __attribute__((ext_vector_type(4)));

// ---------------------------------------------------------------------------
// Phase 1+2 fused: embedding gather + L2 normalize + U = emb @ W_hi^T + b
// (unchanged — proven, ~0.7 ms)
// ---------------------------------------------------------------------------
__global__ void __launch_bounds__(256) embed_gemm(
    const int* __restrict__ src, const float* __restrict__ W,
    const float* __restrict__ Whi, const float* __restrict__ bias,
    float* __restrict__ U) {
  __shared__ float4 se[BT][256];
  __shared__ float  sw[BT][4];

  const int tid  = threadIdx.x;
  const int wv   = tid >> 6;
  const int lane = tid & 63;
  const int t0   = blockIdx.x * BT;

  #pragma unroll
  for (int i = 0; i < BT; i++) {
    const int idx = src[t0 + i];
    float4 v = ((const float4*)(W + (size_t)idx * HID))[tid];
    se[i][tid] = v;
    float ss = v.x*v.x + v.y*v.y + v.z*v.z + v.w*v.w;
    ss += __shfl_xor(ss, 1);  ss += __shfl_xor(ss, 2);  ss += __shfl_xor(ss, 4);
    ss += __shfl_xor(ss, 8);  ss += __shfl_xor(ss, 16); ss += __shfl_xor(ss, 32);
    if (lane == 0) sw[i][wv] = ss;
  }
  __syncthreads();

  float inv_norm[BT];
  #pragma unroll
  for (int i = 0; i < BT; i++) {
    float n = sw[i][0] + sw[i][1] + sw[i][2] + sw[i][3];
    inv_norm[i] = 1.0f / fmaxf(sqrtf(n), 1e-12f);
  }

  float acc[BT][4];
  #pragma unroll
  for (int i = 0; i < BT; i++)
    #pragma unroll
    for (int q = 0; q < 4; q++) acc[i][q] = 0.0f;

  for (int k4 = 0; k4 < HID / 4; k4++) {
    float4 wr[4];
    #pragma unroll
    for (int q = 0; q < 4; q++)
      wr[q] = *(const float4*)(Whi + (size_t)(tid + q * 256) * HID + k4 * 4);
    #pragma unroll
    for (int i = 0; i < BT; i++) {
      float4 e = se[i][k4];
      #pragma unroll
      for (int q = 0; q < 4; q++)
        acc[i][q] += wr[q].x*e.x + wr[q].y*e.y + wr[q].z*e.z + wr[q].w*e.w;
    }
  }

  #pragma unroll
  for (int i = 0; i < BT; i++) {
    #pragma unroll
    for (int q = 0; q < 4; q++) {
      const int j = tid + q * 256;
      U[(size_t)(t0 + i) * HID + j] = acc[i][q] * inv_norm[i] + bias[j];
    }
  }
}

// ---------------------------------------------------------------------------
// Poll-set check: all 16 of this lane's biased values inside (Bc-1.5, Bc+1.5)?
// Window bases alternate {2,6} per generation; |h|<=1 puts valid data in
// [Bc-1, Bc+1]; stale data, zeros, and 0xAA poison (-3e-13) all fail.
// ---------------------------------------------------------------------------
__device__ __forceinline__ bool chk4(const v4f h0v, const v4f h1v,
                                     const v4f h2v, const v4f h3v, float Bc) {
  v4f d0 = h0v - Bc, d1 = h1v - Bc, d2 = h2v - Bc, d3 = h3v - Bc;
  float m0 = fmaxf(fmaxf(fabsf(d0.x), fabsf(d0.y)), fmaxf(fabsf(d0.z), fabsf(d0.w)));
  float m1 = fmaxf(fmaxf(fabsf(d1.x), fabsf(d1.y)), fmaxf(fabsf(d1.z), fabsf(d1.w)));
  float m2 = fmaxf(fmaxf(fabsf(d2.x), fabsf(d2.y)), fmaxf(fabsf(d2.z), fabsf(d2.w)));
  float m3 = fmaxf(fmaxf(fabsf(d3.x), fabsf(d3.y)), fmaxf(fabsf(d3.z), fabsf(d3.w)));
  float m = fmaxf(fmaxf(m0, m1), fmaxf(m2, m3));
  return __all(m < 1.5f) != 0;
}

// ---------------------------------------------------------------------------
// Phase 3: persistent RNN, data-as-flag sync, coalesced SERIALIZED polling.
// SOUNDNESS RULE (R3 post-mortem): every inline-asm block that issues VMEM
// ends with s_waitcnt vmcnt(0) — no load/store ever survives past its asm
// block, so no asynchronous register write can land in a reallocated VGPR.
//
// Wave gw owns rows r0..r0+3 (r0 = gw*4). Lane l owns h[k], k in [16l,16l+16):
// one poll attempt = 4 dwordx4/lane; the wave's 64 lanes cover the 4 KB slot
// exactly once, contiguously (perfectly coalesced, no redundancy).
// Per-lane partial dots for 4 rows, per-lane de-bias (algebraically exact),
// 6-level shfl_xor butterfly x4 chains, lanes 0..3 tanh + publish.
// ---------------------------------------------------------------------------
__global__ void __launch_bounds__(256) rnn_seq(
    const float* __restrict__ Whh, const float* __restrict__ U,
    const float* __restrict__ h0, float* __restrict__ out,
    float* __restrict__ hbuf) {
  const int tid  = threadIdx.x;
  const int lane = tid & 63;
  const int gw   = blockIdx.x * 4 + (tid >> 6);   // 0..255
  const int r0   = gw * 4;                        // first of this wave's 4 rows
  const int k0   = lane * 16;                     // this lane's k-range start

  // W_hh fragments: w[r*4+i] = Whh[r0+r][k0 + 4i .. +3]; Sv[r] = per-lane sum
  v4f w[16];
  float4 Sv;
  #pragma unroll
  for (int r = 0; r < 4; r++) {
    const v4f* wp = (const v4f*)(Whh + (size_t)(r0 + r) * HID + k0);
    float s = 0.0f;
    #pragma unroll
    for (int i = 0; i < 4; i++) {
      w[r * 4 + i] = wp[i];
      s += w[r*4+i].x + w[r*4+i].y + w[r*4+i].z + w[r*4+i].w;
    }
    (&Sv.x)[r] = s;
  }

  // publish row 0 (slot 0, window base 2.0) + raw row 0 to out
  if (lane < 4) {
    float rv = h0[r0 + lane];
    out[r0 + lane] = rv;
    float tv = rv + 2.0f;
    const float* dst = hbuf + r0 + lane;
    asm volatile("global_store_dword %0, %1, off sc0 sc1\n\t"
                 "s_waitcnt vmcnt(0)"
                 :: "v"(dst), "v"(tv) : "memory");
  }

  #pragma unroll 1
  for (int t = 0; t < SEQ; t++) {
    const float Bc = 2.0f + 4.0f * (float)((t >> 2) & 1);
    const float* src = hbuf + ((t & 3) << 10) + k0;
    const float* up  = U + (size_t)t * HID + r0 + (lane & 3);

    v4f A0, A1, A2, A3;
    float u;

    // first attempt rides together with the u-load (shared round trip)
    asm volatile(
      "global_load_dword   %4, %6, off sc0 sc1\n\t"
      "global_load_dwordx4 %0, %5, off sc0 sc1\n\t"
      "global_load_dwordx4 %1, %5, off offset:16 sc0 sc1\n\t"
      "global_load_dwordx4 %2, %5, off offset:32 sc0 sc1\n\t"
      "global_load_dwordx4 %3, %5, off offset:48 sc0 sc1\n\t"
      "s_waitcnt vmcnt(0)"
      : "=&v"(A0), "=&v"(A1), "=&v"(A2), "=&v"(A3), "=&v"(u)
      : "v"(src), "v"(up)
      : "memory");

    while (!chk4(A0, A1, A2, A3, Bc)) {
      asm volatile(
        "global_load_dwordx4 %0, %4, off sc0 sc1\n\t"
        "global_load_dwordx4 %1, %4, off offset:16 sc0 sc1\n\t"
        "global_load_dwordx4 %2, %4, off offset:32 sc0 sc1\n\t"
        "global_load_dwordx4 %3, %4, off offset:48 sc0 sc1\n\t"
        "s_waitcnt vmcnt(0)"
        : "=&v"(A0), "=&v"(A1), "=&v"(A2), "=&v"(A3)
        : "v"(src) : "memory");
    }

    // per-lane partial dots for 4 rows + per-lane de-bias (exact)
    float a0 = 0.f, a1 = 0.f, a2 = 0.f, a3 = 0.f;
    {
      v4f hh[4] = {A0, A1, A2, A3};
      #pragma unroll
      for (int i = 0; i < 4; i++) {
        a0 += w[0*4+i].x*hh[i].x + w[0*4+i].y*hh[i].y + w[0*4+i].z*hh[i].z + w[0*4+i].w*hh[i].w;
        a1 += w[1*4+i].x*hh[i].x + w[1*4+i].y*hh[i].y + w[1*4+i].z*hh[i].z + w[1*4+i].w*hh[i].w;
        a2 += w[2*4+i].x*hh[i].x + w[2*4+i].y*hh[i].y + w[2*4+i].z*hh[i].z + w[2*4+i].w*hh[i].w;
        a3 += w[3*4+i].x*hh[i].x + w[3*4+i].y*hh[i].y + w[3*4+i].z*hh[i].z + w[3*4+i].w*hh[i].w;
      }
    }
    a0 -= Bc * Sv.x;  a1 -= Bc * Sv.y;  a2 -= Bc * Sv.z;  a3 -= Bc * Sv.w;

    // butterfly reduce across 64 lanes (4 interleaved chains)
    #pragma unroll
    for (int m = 1; m <= 32; m <<= 1) {
      a0 += __shfl_xor(a0, m);
      a1 += __shfl_xor(a1, m);
      a2 += __shfl_xor(a2, m);
      a3 += __shfl_xor(a3, m);
    }

    // lanes 0..3 finalize rows r0..r0+3
    float y01 = (lane & 1) ? a1 : a0;
    float y23 = (lane & 1) ? a3 : a2;
    float y   = (lane & 2) ? y23 : y01;
    const float hn = tanhf(y + u);

    if (lane < 4) {
      // publish first (critical path for every other wave), then raw output
      const float Bp = 2.0f + 4.0f * (float)(((t + 1) >> 2) & 1);
      float tv = hn + Bp;
      const float* dst = hbuf + (((t + 1) & 3) << 10) + r0 + lane;
      asm volatile("global_store_dword %0, %1, off sc0 sc1"
                   :: "v"(dst), "v"(tv) : "memory");
      out[(size_t)(t + 1) * HID + r0 + lane] = hn;
      // stores left in flight are drained by the next iteration's first
      // vmcnt(0) poll — they have no destination registers to corrupt.
    }
  }
}

// ---------------------------------------------------------------------------
extern "C" void kernel_launch(void* const* d_in, const int* in_sizes, int n_in,
                              void* d_out, int out_size, void* d_ws, size_t ws_size,
                              hipStream_t stream) {
  const int*   src = (const int*)  d_in[0];
  const float* W   = (const float*)d_in[1];
  const float* h0  = (const float*)d_in[2];
  const float* Whi = (const float*)d_in[3];
  const float* Whh = (const float*)d_in[4];
  const float* b   = (const float*)d_in[5];
  float* out = (float*)d_out;

  float* U    = (float*)d_ws;                                              // 16 MB
  float* hbuf = (float*)((char*)d_ws + (size_t)SEQ * HID * sizeof(float)); // 16 KB, 4 slots
  // no memset needed: 0xAA poison (-3.03e-13) and zeros fail every tag window

  embed_gemm<<<SEQ / BT, 256, 0, stream>>>(src, W, Whi, b, U);
  rnn_seq<<<NWG, 256, 0, stream>>>(Whh, U, h0, out, hbuf);
}

// Round 7
// 8600.199 us; speedup vs baseline: 1.9068x; 1.9068x over previous
//
#include <hip/hip_runtime.h>
#include <math.h>

#define HID 1024
#define SEQ 4096
#define NWG 64        // 64 WGs x 256 thr; co-resident (64 <= 256 CUs), proven config
#define BT  8         // t-tile for the U GEMM

typedef float v4f __attribute__((ext_vector_type(4)));

// ---------------------------------------------------------------------------
// Phase 1+2 fused: embedding gather + L2 normalize + U = emb @ W_hi^T + b
// (unchanged — proven, ~0.7 ms)
// ---------------------------------------------------------------------------
__global__ void __launch_bounds__(256) embed_gemm(
    const int* __restrict__ src, const float* __restrict__ W,
    const float* __restrict__ Whi, const float* __restrict__ bias,
    float* __restrict__ U) {
  __shared__ float4 se[BT][256];
  __shared__ float  sw[BT][4];

  const int tid  = threadIdx.x;
  const int wv   = tid >> 6;
  const int lane = tid & 63;
  const int t0   = blockIdx.x * BT;

  #pragma unroll
  for (int i = 0; i < BT; i++) {
    const int idx = src[t0 + i];
    float4 v = ((const float4*)(W + (size_t)idx * HID))[tid];
    se[i][tid] = v;
    float ss = v.x*v.x + v.y*v.y + v.z*v.z + v.w*v.w;
    ss += __shfl_xor(ss, 1);  ss += __shfl_xor(ss, 2);  ss += __shfl_xor(ss, 4);
    ss += __shfl_xor(ss, 8);  ss += __shfl_xor(ss, 16); ss += __shfl_xor(ss, 32);
    if (lane == 0) sw[i][wv] = ss;
  }
  __syncthreads();

  float inv_norm[BT];
  #pragma unroll
  for (int i = 0; i < BT; i++) {
    float n = sw[i][0] + sw[i][1] + sw[i][2] + sw[i][3];
    inv_norm[i] = 1.0f / fmaxf(sqrtf(n), 1e-12f);
  }

  float acc[BT][4];
  #pragma unroll
  for (int i = 0; i < BT; i++)
    #pragma unroll
    for (int q = 0; q < 4; q++) acc[i][q] = 0.0f;

  for (int k4 = 0; k4 < HID / 4; k4++) {
    float4 wr[4];
    #pragma unroll
    for (int q = 0; q < 4; q++)
      wr[q] = *(const float4*)(Whi + (size_t)(tid + q * 256) * HID + k4 * 4);
    #pragma unroll
    for (int i = 0; i < BT; i++) {
      float4 e = se[i][k4];
      #pragma unroll
      for (int q = 0; q < 4; q++)
        acc[i][q] += wr[q].x*e.x + wr[q].y*e.y + wr[q].z*e.z + wr[q].w*e.w;
    }
  }

  #pragma unroll
  for (int i = 0; i < BT; i++) {
    #pragma unroll
    for (int q = 0; q < 4; q++) {
      const int j = tid + q * 256;
      U[(size_t)(t0 + i) * HID + j] = acc[i][q] * inv_norm[i] + bias[j];
    }
  }
}

// ---------------------------------------------------------------------------
// Poll-set check: all 16 of this lane's biased values inside (Bc-1.5, Bc+1.5)?
// Valid data is in [Bc-1, Bc+1]; stale generation (other window), zeros, and
// 0xAA poison (-3.03e-13) all fail.
// ---------------------------------------------------------------------------
__device__ __forceinline__ bool chk4(const v4f h0v, const v4f h1v,
                                     const v4f h2v, const v4f h3v, float Bc) {
  v4f d0 = h0v - Bc, d1 = h1v - Bc, d2 = h2v - Bc, d3 = h3v - Bc;
  float m0 = fmaxf(fmaxf(fabsf(d0.x), fabsf(d0.y)), fmaxf(fabsf(d0.z), fabsf(d0.w)));
  float m1 = fmaxf(fmaxf(fabsf(d1.x), fabsf(d1.y)), fmaxf(fabsf(d1.z), fabsf(d1.w)));
  float m2 = fmaxf(fmaxf(fabsf(d2.x), fabsf(d2.y)), fmaxf(fabsf(d2.z), fabsf(d2.w)));
  float m3 = fmaxf(fmaxf(fabsf(d3.x), fabsf(d3.y)), fmaxf(fabsf(d3.z), fabsf(d3.w)));
  float m = fmaxf(fmaxf(m0, m1), fmaxf(m2, m3));
  return __all(m < 1.5f) != 0;
}

// ---------------------------------------------------------------------------
// Wave-0-only: poll one 4KB slot (contiguous: lane l covers bytes
// [16l,16l+16) at 1KB stride x4), de-bias, relay into LDS. s_sleep backoff
// between failed attempts cuts LLC congestion. Every asm block that issues
// VMEM ends with vmcnt(0) (R3 soundness rule).
// ---------------------------------------------------------------------------
__device__ __forceinline__ void poll_relay(const float* slotbase, float Bc,
                                           float* dst_lds, int lane,
                                           int* sdead) {
  const float* src = slotbase + 4 * lane;
  v4f A0, A1, A2, A3;
  int tries = 0;
  for (;;) {
    asm volatile(
      "global_load_dwordx4 %0, %4, off sc0 sc1\n\t"
      "global_load_dwordx4 %1, %4, off offset:1024 sc0 sc1\n\t"
      "global_load_dwordx4 %2, %4, off offset:2048 sc0 sc1\n\t"
      "global_load_dwordx4 %3, %4, off offset:3072 sc0 sc1\n\t"
      "s_waitcnt vmcnt(0)"
      : "=&v"(A0), "=&v"(A1), "=&v"(A2), "=&v"(A3)
      : "v"(src) : "memory");
    if (chk4(A0, A1, A2, A3, Bc)) break;
    if (++tries > (1 << 20)) { *sdead = 1; break; }   // clean fail, no hang
    __builtin_amdgcn_s_sleep(1);                       // ~64cyc backoff
  }
  A0 -= Bc;  A1 -= Bc;  A2 -= Bc;  A3 -= Bc;           // relay RAW h
  *(v4f*)(dst_lds +   0 + 4 * lane) = A0;              // ds_write_b128, no conflicts
  *(v4f*)(dst_lds + 256 + 4 * lane) = A1;
  *(v4f*)(dst_lds + 512 + 4 * lane) = A2;
  *(v4f*)(dst_lds + 768 + 4 * lane) = A3;
}

// ---------------------------------------------------------------------------
// Phase 3: persistent RNN, LLC data-as-flag sync, WG-level poller + LDS relay.
// WG b owns rows b*16..b*16+15; wave w owns rows rw=b*16+w*4..+3; lane l owns
// k in {4l..4l+3} + {256,512,768} offsets (contiguous b128 chunks).
// Per step: consume h from double-buffered LDS -> 16 v4f-FMA -> 6-level
// butterfly x4 chains -> lanes 0..3 tanh + publish (1 dword each, the wave's
// 4 rows are 16B contiguous) -> wave 0 publishes then polls next slot into
// the other LDS buffer -> one __syncthreads (doubles as WAR guard).
// Only 64 pollers device-wide (4x fewer LLC requests than R4) + backoff.
// ---------------------------------------------------------------------------
__global__ void __launch_bounds__(256) rnn_seq(
    const float* __restrict__ Whh, const float* __restrict__ U,
    const float* __restrict__ h0, float* __restrict__ out,
    float* __restrict__ hbuf) {
  __shared__ float hsh[2][HID];
  __shared__ int   sdead;

  const int tid   = threadIdx.x;
  const int lane  = tid & 63;
  const int w     = tid >> 6;
  const int b     = blockIdx.x;
  const int r0    = b * 16;              // WG's 16 rows
  const int rw    = r0 + w * 4;          // wave's 4 rows
  const int myrow = rw + (lane & 3);     // row this lane finalizes u for

  if (tid == 0) sdead = 0;

  // init publish (wave 0 lanes 0..15): rows r0..r0+15 into slot 0, base 2.0
  if (tid < 16) {
    float rv = h0[r0 + tid];
    out[r0 + tid] = rv;
    float tv = rv + 2.0f;
    const float* dst = hbuf + r0 + tid;
    asm volatile("global_store_dword %0, %1, off sc0 sc1"
                 :: "v"(dst), "v"(tv) : "memory");
  }

  // W_hh fragments: wreg[r][c] = Whh[rw+r][c*256 + 4l .. +3]
  v4f wreg[4][4];
  #pragma unroll
  for (int r = 0; r < 4; r++)
    #pragma unroll
    for (int c = 0; c < 4; c++)
      wreg[r][c] = *(const v4f*)(Whh + (size_t)(rw + r) * HID + c * 256 + 4 * lane);

  float u_cur = U[myrow];   // step-0 input

  // prologue: wave 0 polls slot 0 (row 0, base 2.0) into hsh[0]
  if (w == 0) poll_relay(hbuf, 2.0f, hsh[0], lane, &sdead);
  __syncthreads();

  #pragma unroll 1
  for (int t = 0; t < SEQ; t++) {
    if (sdead) break;   // uniform after the preceding barrier

    // consume relayed h (raw, de-biased) — conflict-free ds_read_b128
    const float* hp = hsh[t & 1];
    v4f hd0 = *(const v4f*)(hp +   0 + 4 * lane);
    v4f hd1 = *(const v4f*)(hp + 256 + 4 * lane);
    v4f hd2 = *(const v4f*)(hp + 512 + 4 * lane);
    v4f hd3 = *(const v4f*)(hp + 768 + 4 * lane);

    float a[4];
    #pragma unroll
    for (int r = 0; r < 4; r++) {
      a[r] = wreg[r][0].x*hd0.x + wreg[r][0].y*hd0.y + wreg[r][0].z*hd0.z + wreg[r][0].w*hd0.w
           + wreg[r][1].x*hd1.x + wreg[r][1].y*hd1.y + wreg[r][1].z*hd1.z + wreg[r][1].w*hd1.w
           + wreg[r][2].x*hd2.x + wreg[r][2].y*hd2.y + wreg[r][2].z*hd2.z + wreg[r][2].w*hd2.w
           + wreg[r][3].x*hd3.x + wreg[r][3].y*hd3.y + wreg[r][3].z*hd3.z + wreg[r][3].w*hd3.w;
    }

    // butterfly reduce across 64 lanes (4 interleaved chains)
    #pragma unroll
    for (int m = 1; m <= 32; m <<= 1) {
      a[0] += __shfl_xor(a[0], m);
      a[1] += __shfl_xor(a[1], m);
      a[2] += __shfl_xor(a[2], m);
      a[3] += __shfl_xor(a[3], m);
    }

    // lane l (0..3) finalizes row rw + l
    float y01 = (lane & 1) ? a[1] : a[0];
    float y23 = (lane & 1) ? a[3] : a[2];
    float y   = (lane & 2) ? y23 : y01;
    const float hn = tanhf(y + u_cur);

    const float Bp = 2.0f + 4.0f * (float)(((t + 1) >> 2) & 1);
    if (lane < 4) {
      out[(size_t)(t + 1) * HID + rw + lane] = hn;   // raw output
      float tv = hn + Bp;
      const float* dst = hbuf + (((t + 1) & 3) << 10) + rw + lane;
      asm volatile("global_store_dword %0, %1, off sc0 sc1"
                   :: "v"(dst), "v"(tv) : "memory");
      // fire-and-forget: no dest regs; drained by the next vmcnt(0).
    }

    // prefetch next step's U row (h-independent)
    float u_next = U[(size_t)((t + 1 < SEQ) ? t + 1 : t) * HID + myrow];

    // wave 0: poll next row into the other LDS buffer (after own publish)
    if (w == 0 && t + 1 < SEQ)
      poll_relay(hbuf + (((t + 1) & 3) << 10), Bp, hsh[(t + 1) & 1], lane, &sdead);

    __syncthreads();   // relay visible to all; doubles as WAR guard on hsh
    u_cur = u_next;
  }
}

// ---------------------------------------------------------------------------
extern "C" void kernel_launch(void* const* d_in, const int* in_sizes, int n_in,
                              void* d_out, int out_size, void* d_ws, size_t ws_size,
                              hipStream_t stream) {
  const int*   src = (const int*)  d_in[0];
  const float* W   = (const float*)d_in[1];
  const float* h0  = (const float*)d_in[2];
  const float* Whi = (const float*)d_in[3];
  const float* Whh = (const float*)d_in[4];
  const float* b   = (const float*)d_in[5];
  float* out = (float*)d_out;

  float* U    = (float*)d_ws;                                              // 16 MB
  float* hbuf = (float*)((char*)d_ws + (size_t)SEQ * HID * sizeof(float)); // 16 KB, 4 slots
  // d_ws re-poisoned to 0xAA before every launch: poison fails every tag
  // window, so no memset and no cross-replay staleness.

  embed_gemm<<<SEQ / BT, 256, 0, stream>>>(src, W, Whi, b, U);
  rnn_seq<<<NWG, 256, 0, stream>>>(Whh, U, h0, out, hbuf);
}